// Round 5
// baseline (304.769 us; speedup 1.0000x reference)
//
#include <hip/hip_runtime.h>
#include <math.h>

// MoE gate: gate = inp[16384,2048]f32 @ W[64,2048]^T + b[64]; top-2; softmax.
// d_out (float32): [tokens*2] indices-as-floats, then [tokens*2] scores.
//
// Round 7: scalar-W / A-in-registers gate, compile-safe sizing.
// Rounds 0/2/3 plateau at VALUBusy 31-42%: the 4x4-from-LDS loop is
// LDS-issue-coupled (2 ds_read_b128 per 16 FMAs). Round-6 removed that but
// used a 2048-FMA unrolled body + acc[64] (suspected compile blowup ->
// container failure). This round keeps the mechanism, caps body size:
//   - lane = token (64 tokens/wave); 16 experts/wave in acc[16];
//     4 waves/block cover 64 experts; 4 split-K blocks (bitwise-safe).
//   - W addresses wave-uniform (readfirstlane expert base) -> s_load path:
//     no LDS, no per-FMA VMEM issue. A via 8KB LDS tile -> 8 regs per
//     sub-chunk, reused across 16 experts (LDS ~0.06 B/FLOP).
//   - inner unrolled body = 16 exp x 8 k = 128 FMAs. kc/sub loops pinned
//     with #pragma unroll 1.
//   - 4096 waves = 4/SIMD (round-6 had 1/SIMD: no latency hiding).
// Accumulation: one ascending-k fmaf chain per (token,expert,split);
// unchanged verified reduce kernel sums splits 0..3 then bias -> absmax 0.

#define KDIM 2048
#define NEXP 64
#define TM   64                  // tokens per block (= lanes per wave)
#define SPLITS 4
#define KSPLIT (KDIM / SPLITS)   // 512
#define KR   32                  // k-chunk staged per iteration
#define LDST 65                  // padded token stride (bank-conflict-free)
#define EPW  16                  // experts per wave

__global__ __launch_bounds__(256, 4) void gate_partial_kernel(
    const float* __restrict__ inp,
    const float* __restrict__ W,
    float* __restrict__ partial,   // [SPLITS][tokens][NEXP]
    int tokens)
{
    __shared__ float As[KR][LDST];   // As[k][token], 8320 B

    const int tid     = threadIdx.x;
    const int lane    = tid & 63;                                  // token lane
    const int wv      = __builtin_amdgcn_readfirstlane(tid >> 6);  // wave 0..3
    const int tokBase = blockIdx.x * TM;
    const int split   = blockIdx.y;
    const int k0      = split * KSPLIT;
    const int eBase   = wv * EPW;   // SGPR -> W addresses stay uniform

    // coalesced A staging: 256 threads, 64 rows x 32 k, 2 float4 passes
    const int trow = tid >> 3;          // 0..31
    const int tcol = (tid & 7) << 2;    // 0,4,...,28

    const float* aPtr = inp + (size_t)(tokBase + trow) * KDIM + k0 + tcol;
    const float* wB   = W + (size_t)eBase * KDIM + k0;   // wave-uniform

    float4 pre0 = *(const float4*)(aPtr);
    float4 pre1 = *(const float4*)(aPtr + (size_t)32 * KDIM);

    float acc[EPW];
    #pragma unroll
    for (int e = 0; e < EPW; ++e) acc[e] = 0.0f;

    #pragma unroll 1
    for (int kc = 0; kc < KSPLIT; kc += KR) {
        __syncthreads();   // previous chunk's As reads complete
        #pragma unroll
        for (int c = 0; c < 4; ++c) {
            As[tcol + c][trow]      = ((const float*)&pre0)[c];
            As[tcol + c][trow + 32] = ((const float*)&pre1)[c];
        }
        __syncthreads();
        if (kc + KR < KSPLIT) {   // issue next chunk; lands during compute
            pre0 = *(const float4*)(aPtr + kc + KR);
            pre1 = *(const float4*)(aPtr + kc + KR + (size_t)32 * KDIM);
        }

        #pragma unroll 1
        for (int sub = 0; sub < 4; ++sub) {
            // 8 A values for this lane's token, reused across 16 experts.
            // As[j][lane]: addr = j*65 + lane -> stride-1 across lanes, free.
            float a[8];
            #pragma unroll
            for (int jj = 0; jj < 8; ++jj) a[jj] = As[sub * 8 + jj][lane];

            const float* wr = wB + kc + sub * 8;
            #pragma unroll
            for (int e = 0; e < EPW; ++e) {
                const float* we = wr + (size_t)e * KDIM;   // uniform -> s_load
                float w[8];
                #pragma unroll
                for (int jj = 0; jj < 8; ++jj) w[jj] = we[jj];
                #pragma unroll
                for (int jj = 0; jj < 8; ++jj)   // ascending k, single chain
                    acc[e] = fmaf(a[jj], w[jj], acc[e]);
            }
        }
    }

    // write this wave's 16 experts for its 64 tokens
    float* pOut = partial + ((size_t)split * tokens + tokBase + lane) * NEXP + eBase;
    #pragma unroll
    for (int c = 0; c < 4; ++c)
        *(float4*)(pOut + 4 * c) =
            make_float4(acc[4*c], acc[4*c+1], acc[4*c+2], acc[4*c+3]);
}

__global__ __launch_bounds__(256) void reduce_topk_kernel(
    const float* __restrict__ partial,
    const float* __restrict__ bias,
    float* __restrict__ out,
    int tokens, int S)
{
    const int tid = threadIdx.x;
    const int tx  = tid & 15;          // experts 4*tx..4*tx+3
    const int ty  = tid >> 4;          // 16 tokens per block
    const int token = blockIdx.x * 16 + ty;
    const int eBase = tx << 2;

    float4 v = make_float4(0.f, 0.f, 0.f, 0.f);
    for (int s = 0; s < S; ++s) {
        const float4 p = *(const float4*)&partial[((size_t)s * tokens + token) * NEXP + eBase];
        v.x += p.x; v.y += p.y; v.z += p.z; v.w += p.w;
    }
    const float4 bv = *(const float4*)&bias[eBase];
    float g[4] = { v.x + bv.x, v.y + bv.y, v.z + bv.z, v.w + bv.w };

    // local top-2 (ascending scan keeps lower index on ties, matching lax.top_k)
    float v1 = g[0]; int i1 = eBase;
    float v2 = -INFINITY; int i2 = -1;
    #pragma unroll
    for (int c = 1; c < 4; ++c) {
        const float vv = g[c];
        const int   ii = eBase + c;
        if (vv > v1)      { v2 = v1; i2 = i1; v1 = vv; i1 = ii; }
        else if (vv > v2) { v2 = vv; i2 = ii; }
    }
    // 16-lane butterfly merge
    #pragma unroll
    for (int m = 1; m <= 8; m <<= 1) {
        const float ov1 = __shfl_xor(v1, m);
        const int   oi1 = __shfl_xor(i1, m);
        const float ov2 = __shfl_xor(v2, m);
        const int   oi2 = __shfl_xor(i2, m);
        const bool aw = (v1 > ov1) || (v1 == ov1 && i1 < oi1);
        const float nv1 = aw ? v1  : ov1;  const int ni1 = aw ? i1  : oi1;
        const float lv  = aw ? ov1 : v1;   const int li  = aw ? oi1 : i1;
        const float sv  = aw ? v2  : ov2;  const int si  = aw ? i2  : oi2;
        const bool sw = (sv > lv) || (sv == lv && si < li);
        v1 = nv1; i1 = ni1;
        v2 = sw ? sv : lv; i2 = sw ? si : li;
    }
    if (tx == 0) {
        const float e2 = expf(v2 - v1);
        const float denom = 1.0f + e2;
        out[2 * token]     = (float)i1;
        out[2 * token + 1] = (float)i2;
        out[tokens * 2 + 2 * token]     = 1.0f / denom;
        out[tokens * 2 + 2 * token + 1] = e2 / denom;
    }
}

extern "C" void kernel_launch(void* const* d_in, const int* in_sizes, int n_in,
                              void* d_out, int out_size, void* d_ws, size_t ws_size,
                              hipStream_t stream) {
    const float* inp  = (const float*)d_in[0];
    const float* W    = (const float*)d_in[1];
    const float* bias = (const float*)d_in[2];
    float* out = (float*)d_out;
    float* partial = (float*)d_ws;
    (void)n_in; (void)out_size; (void)ws_size;

    const int tokens = in_sizes[0] / KDIM;   // 16384

    dim3 grid(tokens / TM, SPLITS);
    gate_partial_kernel<<<grid, 256, 0, stream>>>(inp, W, partial, tokens);
    reduce_topk_kernel<<<tokens / 16, 256, 0, stream>>>(partial, bias, out, tokens, SPLITS);
}

// Round 6
// 215.066 us; speedup vs baseline: 1.4171x; 1.4171x over previous
//
#include <hip/hip_runtime.h>
#include <math.h>

// MoE gate: gate = inp[16384,2048]f32 @ W[64,2048]^T + b[64]; top-2; softmax.
// d_out (float32): [tokens*2] indices-as-floats, then [tokens*2] scores.
//
// Round 8: r0 structure + double-buffered LDS (one barrier per K-tile).
// Ledger: r0 (2-barrier split-K) = 214us total, gate ~47us vs 27.3us FMA
// floor; fused-1024 (r4) 84us gate; TM32 (r5) 97us; scalar-W (r7) 164us
// (s_load lgkmcnt(0) latency-poisoned). The remaining r0 gap is the
// per-tile write->barrier->read->barrier drain (~780cy/tile). This round:
// write tile t+1 into buf[nxt] AFTER computing buf[cur] (disjoint buffers,
// no hazard), single __syncthreads() per tile covers both visibility and
// anti-overwrite. Global prefetch distance ~2 tiles (~1100cy > 900cy HBM).
// Thread map, 4x4 blocking, staging layout, S=4, ascending-k accumulation,
// and the reduce kernel are byte-identical to r0 -> absmax stays 0.0.

#define KDIM 2048
#define NEXP 64
#define TM 64
#define BK 32
#define LDSS 68   // 64 + 4 pad: 272 B row stride (mult of 16 -> b128-aligned)

__global__ __launch_bounds__(256) void gate_partial_kernel(
    const float* __restrict__ inp,
    const float* __restrict__ W,
    float* __restrict__ partial,   // [S][tokens][NEXP]
    int tokens, int kPerSplit)
{
    __shared__ float As[2][BK][LDSS];   // As[buf][k][token]  (17.4 KB)
    __shared__ float Ws[2][BK][LDSS];   // Ws[buf][k][expert] (17.4 KB)

    const int tid = threadIdx.x;
    const int tx  = tid & 15;        // experts 4*tx..4*tx+3
    const int ty  = tid >> 4;        // tokens 4*ty..4*ty+3
    const int tokBase = blockIdx.x * TM;
    const int split   = blockIdx.y;
    const int k0      = split * kPerSplit;

    // staging map: 64 rows x 32 cols f32 per tile, 2 passes of float4
    const int lrow = tid >> 3;          // 0..31
    const int lcol = (tid & 7) << 2;    // 0,4,...,28

    const float* aPtr0 = inp + (size_t)(tokBase + lrow)      * KDIM + k0 + lcol;
    const float* aPtr1 = inp + (size_t)(tokBase + lrow + 32) * KDIM + k0 + lcol;
    const float* wPtr0 = W   + (size_t)lrow        * KDIM + k0 + lcol;
    const float* wPtr1 = W   + (size_t)(lrow + 32) * KDIM + k0 + lcol;

    float4 aReg0 = *(const float4*)(aPtr0);
    float4 aReg1 = *(const float4*)(aPtr1);
    float4 wReg0 = *(const float4*)(wPtr0);
    float4 wReg1 = *(const float4*)(wPtr1);

    const int NT = kPerSplit / BK;

    // stage tile 0 into buffer 0
    #pragma unroll
    for (int c = 0; c < 4; ++c) {
        As[0][lcol + c][lrow]      = ((const float*)&aReg0)[c];
        As[0][lcol + c][lrow + 32] = ((const float*)&aReg1)[c];
        Ws[0][lcol + c][lrow]      = ((const float*)&wReg0)[c];
        Ws[0][lcol + c][lrow + 32] = ((const float*)&wReg1)[c];
    }
    // issue tile 1 loads; they fly during barrier + tile-0 compute
    if (NT > 1) {
        aReg0 = *(const float4*)(aPtr0 + BK);
        aReg1 = *(const float4*)(aPtr1 + BK);
        wReg0 = *(const float4*)(wPtr0 + BK);
        wReg1 = *(const float4*)(wPtr1 + BK);
    }
    __syncthreads();

    float acc[4][4];
    #pragma unroll
    for (int r = 0; r < 4; ++r)
        #pragma unroll
        for (int c = 0; c < 4; ++c) acc[r][c] = 0.0f;

    for (int kt = 0; kt < NT; ++kt) {
        const int cur = kt & 1;
        const int nxt = cur ^ 1;

        // compute current tile (same 4x4 kk-loop as r0; ascending k)
        #pragma unroll 8
        for (int kk = 0; kk < BK; ++kk) {
            const float4 av = *(const float4*)&As[cur][kk][ty << 2];
            const float4 wv = *(const float4*)&Ws[cur][kk][tx << 2];
            const float a[4] = {av.x, av.y, av.z, av.w};
            const float w[4] = {wv.x, wv.y, wv.z, wv.w};
            #pragma unroll
            for (int r = 0; r < 4; ++r)
                #pragma unroll
                for (int c = 0; c < 4; ++c)
                    acc[r][c] = fmaf(a[r], w[c], acc[r][c]);
        }

        if (kt + 1 < NT) {
            // stage tile kt+1 into the other buffer (no hazard: all waves'
            // reads this tile are from buf[cur]; writes visible after the
            // single barrier below)
            #pragma unroll
            for (int c = 0; c < 4; ++c) {
                As[nxt][lcol + c][lrow]      = ((const float*)&aReg0)[c];
                As[nxt][lcol + c][lrow + 32] = ((const float*)&aReg1)[c];
                Ws[nxt][lcol + c][lrow]      = ((const float*)&wReg0)[c];
                Ws[nxt][lcol + c][lrow + 32] = ((const float*)&wReg1)[c];
            }
            // issue tile kt+2 loads; consumed at the END of tile kt+1
            // (one full tile ~1100cy in flight)
            if (kt + 2 < NT) {
                const int off = (kt + 2) * BK;
                aReg0 = *(const float4*)(aPtr0 + off);
                aReg1 = *(const float4*)(aPtr1 + off);
                wReg0 = *(const float4*)(wPtr0 + off);
                wReg1 = *(const float4*)(wPtr1 + off);
            }
        }
        // single barrier per tile: (a) buf[nxt] writes visible before next
        // compute, (b) all buf[cur] reads done before tile kt+2 overwrites it
        __syncthreads();
    }

    // write partials: [split][token][expert], float4 over experts, coalesced in tx
    const int eBase = tx << 2;
    #pragma unroll
    for (int r = 0; r < 4; ++r) {
        const int token = tokBase + (ty << 2) + r;
        float4 v = make_float4(acc[r][0], acc[r][1], acc[r][2], acc[r][3]);
        *(float4*)&partial[((size_t)split * tokens + token) * NEXP + eBase] = v;
    }
}

__global__ __launch_bounds__(256) void reduce_topk_kernel(
    const float* __restrict__ partial,
    const float* __restrict__ bias,
    float* __restrict__ out,
    int tokens, int S)
{
    const int tid = threadIdx.x;
    const int tx  = tid & 15;          // experts 4*tx..4*tx+3
    const int ty  = tid >> 4;          // 16 tokens per block
    const int token = blockIdx.x * 16 + ty;
    const int eBase = tx << 2;

    float4 v = make_float4(0.f, 0.f, 0.f, 0.f);
    for (int s = 0; s < S; ++s) {
        const float4 p = *(const float4*)&partial[((size_t)s * tokens + token) * NEXP + eBase];
        v.x += p.x; v.y += p.y; v.z += p.z; v.w += p.w;
    }
    const float4 bv = *(const float4*)&bias[eBase];
    float g[4] = { v.x + bv.x, v.y + bv.y, v.z + bv.z, v.w + bv.w };

    // local top-2 (ascending scan keeps lower index on ties, matching lax.top_k)
    float v1 = g[0]; int i1 = eBase;
    float v2 = -INFINITY; int i2 = -1;
    #pragma unroll
    for (int c = 1; c < 4; ++c) {
        const float vv = g[c];
        const int   ii = eBase + c;
        if (vv > v1)      { v2 = v1; i2 = i1; v1 = vv; i1 = ii; }
        else if (vv > v2) { v2 = vv; i2 = ii; }
    }
    // 16-lane butterfly merge
    #pragma unroll
    for (int m = 1; m <= 8; m <<= 1) {
        const float ov1 = __shfl_xor(v1, m);
        const int   oi1 = __shfl_xor(i1, m);
        const float ov2 = __shfl_xor(v2, m);
        const int   oi2 = __shfl_xor(i2, m);
        const bool aw = (v1 > ov1) || (v1 == ov1 && i1 < oi1);
        const float nv1 = aw ? v1  : ov1;  const int ni1 = aw ? i1  : oi1;
        const float lv  = aw ? ov1 : v1;   const int li  = aw ? oi1 : i1;
        const float sv  = aw ? v2  : ov2;  const int si  = aw ? i2  : oi2;
        const bool sw = (sv > lv) || (sv == lv && si < li);
        v1 = nv1; i1 = ni1;
        v2 = sw ? sv : lv; i2 = sw ? si : li;
    }
    if (tx == 0) {
        const float e2 = expf(v2 - v1);
        const float denom = 1.0f + e2;
        out[2 * token]     = (float)i1;
        out[2 * token + 1] = (float)i2;
        out[tokens * 2 + 2 * token]     = 1.0f / denom;
        out[tokens * 2 + 2 * token + 1] = e2 / denom;
    }
}

extern "C" void kernel_launch(void* const* d_in, const int* in_sizes, int n_in,
                              void* d_out, int out_size, void* d_ws, size_t ws_size,
                              hipStream_t stream) {
    const float* inp  = (const float*)d_in[0];
    const float* W    = (const float*)d_in[1];
    const float* bias = (const float*)d_in[2];
    float* out = (float*)d_out;
    float* partial = (float*)d_ws;

    const int tokens = in_sizes[0] / KDIM;   // 16384

    // pick largest split S in {4,2,1} whose partial buffer fits d_ws
    int S = 4;
    while (S > 1 && (size_t)S * tokens * NEXP * sizeof(float) > ws_size) S >>= 1;
    const int kPerSplit = KDIM / S;

    dim3 grid(tokens / TM, S);
    gate_partial_kernel<<<grid, 256, 0, stream>>>(inp, W, partial, tokens, kPerSplit);
    reduce_topk_kernel<<<tokens / 16, 256, 0, stream>>>(partial, bias, out, tokens, S);
}

// Round 7
// 214.771 us; speedup vs baseline: 1.4190x; 1.0014x over previous
//
#include <hip/hip_runtime.h>
#include <math.h>

// MoE gate: gate = inp[16384,2048]f32 @ W[64,2048]^T + b[64]; top-2; softmax.
// d_out (float32): [tokens*2] indices-as-floats, then [tokens*2] scores.
//
// Round 9: 4-token x 8-expert per-thread blocking (0.75 B/FLOP from LDS).
// Ledger: r0 two-kernel split-K = 214us (gate ~65us vs 27.3us VALU floor);
// dbuf (r8) neutral -> barrier drain is NOT the cost. Theory: gate is
// LDS-return-path bound: 4x4 reads 2 ds_read_b128 per 16 FMA = 1 B/FLOP;
// per CU 16 waves x 512 kk x 2 reads x ~8-12cy ~ 55-82us ~= observed.
// This round: 4tok x 8exp = 3 b128 per 32 FMA (0.75 B/FLOP). TM=128,
// 256-thread blocks, grid (128,4) = 2 blocks/CU, 8 waves/CU. S=4 and the
// per-element ascending-k fmaf chain are UNCHANGED -> partials bitwise-
// identical to r0 -> absmax stays 0.0. Reduce kernel byte-identical.

#define KDIM 2048
#define NEXP 64
#define TM 128
#define BK 32
#define LDSA 132  // 128 tokens + 4 pad: 528 B stride (mult of 16 -> b128 ok)
#define LDSW 68   // 64 experts + 4 pad: 272 B stride

__global__ __launch_bounds__(256) void gate_partial_kernel(
    const float* __restrict__ inp,
    const float* __restrict__ W,
    float* __restrict__ partial,   // [S][tokens][NEXP]
    int tokens, int kPerSplit)
{
    __shared__ float As[2][BK][LDSA];   // As[buf][k][token]  (33.8 KB)
    __shared__ float Ws[2][BK][LDSW];   // Ws[buf][k][expert] (17.4 KB)

    const int tid = threadIdx.x;
    const int tx  = tid & 7;         // experts 8*tx..8*tx+7
    const int ty  = tid >> 3;        // tokens 4*ty..4*ty+3 (0..31)
    const int tokBase = blockIdx.x * TM;
    const int split   = blockIdx.y;
    const int k0      = split * kPerSplit;

    // A staging: 128 rows x 32 k; 2 threads/row, 16 k each (4 float4)
    const int arow = tid >> 1;           // 0..127
    const int acol = (tid & 1) << 4;     // 0 or 16
    // W staging: 64 rows x 32 k; 4 threads/row, 8 k each (2 float4)
    const int wrow = tid >> 2;           // 0..63
    const int wcol = (tid & 3) << 3;     // 0,8,16,24

    const float* aPtr = inp + (size_t)(tokBase + arow) * KDIM + k0 + acol;
    const float* wPtr = W   + (size_t)wrow * KDIM + k0 + wcol;

    float4 aReg[4], wReg[2];
    #pragma unroll
    for (int q = 0; q < 4; ++q) aReg[q] = *(const float4*)(aPtr + 4 * q);
    #pragma unroll
    for (int q = 0; q < 2; ++q) wReg[q] = *(const float4*)(wPtr + 4 * q);

    const int NT = kPerSplit / BK;

    // stage tile 0 into buffer 0 (transpose to [k][token]/[k][expert])
    #pragma unroll
    for (int q = 0; q < 4; ++q)
        #pragma unroll
        for (int j = 0; j < 4; ++j)
            As[0][acol + 4 * q + j][arow] = ((const float*)&aReg[q])[j];
    #pragma unroll
    for (int q = 0; q < 2; ++q)
        #pragma unroll
        for (int j = 0; j < 4; ++j)
            Ws[0][wcol + 4 * q + j][wrow] = ((const float*)&wReg[q])[j];

    // issue tile 1 loads; they fly during barrier + tile-0 compute
    if (NT > 1) {
        #pragma unroll
        for (int q = 0; q < 4; ++q) aReg[q] = *(const float4*)(aPtr + BK + 4 * q);
        #pragma unroll
        for (int q = 0; q < 2; ++q) wReg[q] = *(const float4*)(wPtr + BK + 4 * q);
    }
    __syncthreads();

    float acc[4][8];
    #pragma unroll
    for (int r = 0; r < 4; ++r)
        #pragma unroll
        for (int c = 0; c < 8; ++c) acc[r][c] = 0.0f;

    for (int kt = 0; kt < NT; ++kt) {
        const int cur = kt & 1;
        const int nxt = cur ^ 1;

        // compute current tile: per kk, 3 ds_read_b128 feed 32 FMAs
        #pragma unroll 8
        for (int kk = 0; kk < BK; ++kk) {
            const float4 av  = *(const float4*)&As[cur][kk][ty << 2];
            const float4 wv0 = *(const float4*)&Ws[cur][kk][tx << 3];
            const float4 wv1 = *(const float4*)&Ws[cur][kk][(tx << 3) + 4];
            const float a[4] = {av.x, av.y, av.z, av.w};
            const float w[8] = {wv0.x, wv0.y, wv0.z, wv0.w,
                                wv1.x, wv1.y, wv1.z, wv1.w};
            #pragma unroll
            for (int r = 0; r < 4; ++r)
                #pragma unroll
                for (int c = 0; c < 8; ++c)
                    acc[r][c] = fmaf(a[r], w[c], acc[r][c]);
        }

        if (kt + 1 < NT) {
            // stage tile kt+1 into the other buffer
            #pragma unroll
            for (int q = 0; q < 4; ++q)
                #pragma unroll
                for (int j = 0; j < 4; ++j)
                    As[nxt][acol + 4 * q + j][arow] = ((const float*)&aReg[q])[j];
            #pragma unroll
            for (int q = 0; q < 2; ++q)
                #pragma unroll
                for (int j = 0; j < 4; ++j)
                    Ws[nxt][wcol + 4 * q + j][wrow] = ((const float*)&wReg[q])[j];
            // issue tile kt+2 loads (consumed at the end of tile kt+1)
            if (kt + 2 < NT) {
                const int off = (kt + 2) * BK;
                #pragma unroll
                for (int q = 0; q < 4; ++q)
                    aReg[q] = *(const float4*)(aPtr + off + 4 * q);
                #pragma unroll
                for (int q = 0; q < 2; ++q)
                    wReg[q] = *(const float4*)(wPtr + off + 4 * q);
            }
        }
        // single barrier per tile: buf[nxt] visible before next compute AND
        // buf[cur] reads done before tile kt+2 overwrites it
        __syncthreads();
    }

    // write partials: [split][token][expert]; 2 float4 per token row
    const int eBase = tx << 3;
    #pragma unroll
    for (int r = 0; r < 4; ++r) {
        const int token = tokBase + (ty << 2) + r;
        float* p = &partial[((size_t)split * tokens + token) * NEXP + eBase];
        *(float4*)(p)     = make_float4(acc[r][0], acc[r][1], acc[r][2], acc[r][3]);
        *(float4*)(p + 4) = make_float4(acc[r][4], acc[r][5], acc[r][6], acc[r][7]);
    }
}

__global__ __launch_bounds__(256) void reduce_topk_kernel(
    const float* __restrict__ partial,
    const float* __restrict__ bias,
    float* __restrict__ out,
    int tokens, int S)
{
    const int tid = threadIdx.x;
    const int tx  = tid & 15;          // experts 4*tx..4*tx+3
    const int ty  = tid >> 4;          // 16 tokens per block
    const int token = blockIdx.x * 16 + ty;
    const int eBase = tx << 2;

    float4 v = make_float4(0.f, 0.f, 0.f, 0.f);
    for (int s = 0; s < S; ++s) {
        const float4 p = *(const float4*)&partial[((size_t)s * tokens + token) * NEXP + eBase];
        v.x += p.x; v.y += p.y; v.z += p.z; v.w += p.w;
    }
    const float4 bv = *(const float4*)&bias[eBase];
    float g[4] = { v.x + bv.x, v.y + bv.y, v.z + bv.z, v.w + bv.w };

    // local top-2 (ascending scan keeps lower index on ties, matching lax.top_k)
    float v1 = g[0]; int i1 = eBase;
    float v2 = -INFINITY; int i2 = -1;
    #pragma unroll
    for (int c = 1; c < 4; ++c) {
        const float vv = g[c];
        const int   ii = eBase + c;
        if (vv > v1)      { v2 = v1; i2 = i1; v1 = vv; i1 = ii; }
        else if (vv > v2) { v2 = vv; i2 = ii; }
    }
    // 16-lane butterfly merge
    #pragma unroll
    for (int m = 1; m <= 8; m <<= 1) {
        const float ov1 = __shfl_xor(v1, m);
        const int   oi1 = __shfl_xor(i1, m);
        const float ov2 = __shfl_xor(v2, m);
        const int   oi2 = __shfl_xor(i2, m);
        const bool aw = (v1 > ov1) || (v1 == ov1 && i1 < oi1);
        const float nv1 = aw ? v1  : ov1;  const int ni1 = aw ? i1  : oi1;
        const float lv  = aw ? ov1 : v1;   const int li  = aw ? oi1 : i1;
        const float sv  = aw ? v2  : ov2;  const int si  = aw ? i2  : oi2;
        const bool sw = (sv > lv) || (sv == lv && si < li);
        v1 = nv1; i1 = ni1;
        v2 = sw ? sv : lv; i2 = sw ? si : li;
    }
    if (tx == 0) {
        const float e2 = expf(v2 - v1);
        const float denom = 1.0f + e2;
        out[2 * token]     = (float)i1;
        out[2 * token + 1] = (float)i2;
        out[tokens * 2 + 2 * token]     = 1.0f / denom;
        out[tokens * 2 + 2 * token + 1] = e2 / denom;
    }
}

extern "C" void kernel_launch(void* const* d_in, const int* in_sizes, int n_in,
                              void* d_out, int out_size, void* d_ws, size_t ws_size,
                              hipStream_t stream) {
    const float* inp  = (const float*)d_in[0];
    const float* W    = (const float*)d_in[1];
    const float* bias = (const float*)d_in[2];
    float* out = (float*)d_out;
    float* partial = (float*)d_ws;

    const int tokens = in_sizes[0] / KDIM;   // 16384

    // pick largest split S in {4,2,1} whose partial buffer fits d_ws
    int S = 4;
    while (S > 1 && (size_t)S * tokens * NEXP * sizeof(float) > ws_size) S >>= 1;
    const int kPerSplit = KDIM / S;

    dim3 grid(tokens / TM, S);
    gate_partial_kernel<<<grid, 256, 0, stream>>>(inp, W, partial, tokens, kPerSplit);
    reduce_topk_kernel<<<tokens / 16, 256, 0, stream>>>(partial, bias, out, tokens, S);
}